// Round 7
// baseline (1133.738 us; speedup 1.0000x reference)
//
#include <hip/hip_runtime.h>
#include <hip/hip_bf16.h>
#include <cstdint>

#define T_TOK 2048
#define HD 2048
#define ID 1408
#define NE 16
#define TOPK 6

#define BM 128
#define BN 64
#define BK 32

typedef __bf16 bf16x8 __attribute__((ext_vector_type(8)));
typedef float f32x4 __attribute__((ext_vector_type(4)));

typedef const __attribute__((address_space(1))) void* gas1_t;
typedef __attribute__((address_space(3))) void* las3_t;
#define GLDS16(g, l) __builtin_amdgcn_global_load_lds((gas1_t)(g), (las3_t)(l), 16, 0, 0)

// --- small kernels -----------------------------------------------------

__global__ void k_combine(const int* __restrict__ idx, const float* __restrict__ w,
                          float* __restrict__ combine) {
    int t = blockIdx.x * blockDim.x + threadIdx.x;
    if (t >= T_TOK) return;
    int ie[TOPK];
    float fw[TOPK];
#pragma unroll
    for (int k = 0; k < TOPK; k++) { ie[k] = idx[t * TOPK + k]; fw[k] = w[t * TOPK + k]; }
#pragma unroll
    for (int e = 0; e < NE; e++) {
        float s = 0.f;
#pragma unroll
        for (int k = 0; k < TOPK; k++) if (ie[k] == e) s += fw[k];
        combine[t * NE + e] = s;
    }
}

__global__ void k_lists(const float* __restrict__ combine, int* __restrict__ counts,
                        int* __restrict__ tok, float* __restrict__ wts) {
    int t = blockIdx.x * blockDim.x + threadIdx.x;
    if (t >= T_TOK) return;
    for (int e = 0; e < NE; e++) {
        float c = combine[t * NE + e];
        if (c != 0.0f) {
            int p = atomicAdd(&counts[e], 1);
            tok[e * T_TOK + p] = t;
            wts[e * T_TOK + p] = c;
        }
    }
}

__global__ void k_cvt(const float* __restrict__ x, __bf16* __restrict__ xb) {
    int i = (blockIdx.x * 256 + threadIdx.x) * 8;
    float4 a = *(const float4*)(x + i);
    float4 b = *(const float4*)(x + i + 4);
    bf16x8 o;
    o[0] = (__bf16)a.x; o[1] = (__bf16)a.y; o[2] = (__bf16)a.z; o[3] = (__bf16)a.w;
    o[4] = (__bf16)b.x; o[5] = (__bf16)b.y; o[6] = (__bf16)b.z; o[7] = (__bf16)b.w;
    *(bf16x8*)(xb + i) = o;
}

// --- LDS helpers (64-byte rows, BK=32) ---------------------------------
// byte = row*64 + (cb ^ ((row&3)<<4)); worst-case 4-way bank conflict.

__device__ __forceinline__ int swz32(int row, int cb) {
    return row * 64 + (cb ^ ((row & 3) << 4));
}

__device__ __forceinline__ bf16x8 ldfrag32(const __bf16* base, int row, int cb) {
    return *(const bf16x8*)((const char*)base + swz32(row, cb));
}

// 8 fp32 (regs) -> 8 bf16 -> one swizzled 16B LDS store (row in [0,64), cb in {0,16,32,48})
__device__ __forceinline__ void stage8v(char* lds, int row, int cb, float4 f0, float4 f1) {
    bf16x8 o;
    o[0] = (__bf16)f0.x; o[1] = (__bf16)f0.y; o[2] = (__bf16)f0.z; o[3] = (__bf16)f0.w;
    o[4] = (__bf16)f1.x; o[5] = (__bf16)f1.y; o[6] = (__bf16)f1.z; o[7] = (__bf16)f1.w;
    *(bf16x8*)(lds + swz32(row, cb)) = o;
}

// --- GEMM1: act = silu(X@Gg^T) * (X@Gu^T)  ------------------------------
// grid.x = ((e*22 + n) << 4) + m  (m fastest: the ~6 live m-tiles per (e,n)
// run temporally adjacent -> weight panel slices stay L3-hot)
// Single-sync full-dbuf K-loop (R6 schedule) at 32KB LDS -> 4 blocks/CU.

__global__ __launch_bounds__(256, 4) void k_gemm1(
    const __bf16* __restrict__ Xb, const float* __restrict__ gup,
    const int* __restrict__ counts, const int* __restrict__ tok,
    __bf16* __restrict__ act) {
    int x = blockIdx.x;
    int m = x & 15;
    int g = x >> 4;
    int e = g / 22;
    int n0 = (g % 22) * BN;
    int cnt = counts[e];
    int m0 = m * BM;
    if (m0 >= cnt) return;

    __shared__ __align__(16) __bf16 sA[2][BM * BK];
    __shared__ __align__(16) __bf16 sBg[2][BN * BK];
    __shared__ __align__(16) __bf16 sBu[2][BN * BK];

    int tid = threadIdx.x;
    int lane = tid & 63;
    int wid = tid >> 6;            // 4 waves

    // A staging: wave w owns logical rows [32w, 32w+32); 2 GLDS16/thread.
    // LDS linear dest; global source column pre-swizzled (rule #21):
    // lane L, call j: row = 32w + 16j + (L>>2), k-chunk = ((L&3)^((L>>2)&3))*8 bf16
    const __bf16* pA[2];
    int csw = ((lane & 3) ^ ((lane >> 2) & 3)) * 8;
#pragma unroll
    for (int j = 0; j < 2; j++) {
        int r = 32 * wid + 16 * j + (lane >> 2);
        int gg = m0 + r;
        if (gg >= cnt) gg = cnt - 1;
        pA[j] = Xb + (size_t)tok[e * T_TOK + gg] * HD + csw;
    }

    // B staging: thread t -> row t>>2 in [0,64), chunk (t&3)*8 fp32
    int br = tid >> 2, bc = tid & 3;
    const float* gbase = gup + (size_t)e * (2 * ID) * HD;
    const float* bgSrc = gbase + (size_t)(n0 + br) * HD + bc * 8;
    const float* buSrc = gbase + (size_t)(ID + n0 + br) * HD + bc * 8;

    int wm = wid >> 1, wn = wid & 1;          // 2x2 waves over 128x64
    int l15 = lane & 15, lh = lane >> 4;

    f32x4 accg[4][2] = {};
    f32x4 accu[4][2] = {};

    const int NT = HD / BK;   // 64

    // prologue: tile 0
    {
        float4 g0 = ((const float4*)bgSrc)[0], g1 = ((const float4*)bgSrc)[1];
        float4 u0 = ((const float4*)buSrc)[0], u1 = ((const float4*)buSrc)[1];
#pragma unroll
        for (int j = 0; j < 2; j++)
            GLDS16(pA[j], &sA[0][(32 * wid + 16 * j) * BK]);
        stage8v((char*)sBg[0], br, bc * 16, g0, g1);
        stage8v((char*)sBu[0], br, bc * 16, u0, u1);
    }
    __syncthreads();

    for (int k = 0; k < NT; k++) {
        int cur = k & 1, nxt = cur ^ 1;
        bool pf = (k + 1 < NT);
        float4 g0, g1, u0, u1;
        if (pf) {
            int k0 = (k + 1) * BK;
#pragma unroll
            for (int j = 0; j < 2; j++)
                GLDS16(pA[j] + k0, &sA[nxt][(32 * wid + 16 * j) * BK]);
            const float* bg = bgSrc + k0;
            const float* bu = buSrc + k0;
            g0 = ((const float4*)bg)[0]; g1 = ((const float4*)bg)[1];
            u0 = ((const float4*)bu)[0]; u1 = ((const float4*)bu)[1];
        }

        // MFMA phase on tile k (BK=32 -> one MFMA per (fm,fn) per matrix)
        const __bf16* sAc = sA[cur];
        const __bf16* sBgc = sBg[cur];
        const __bf16* sBuc = sBu[cur];
        int cb = lh * 16;
        bf16x8 a[4];
#pragma unroll
        for (int fm = 0; fm < 4; fm++)
            a[fm] = ldfrag32(sAc, wm * 64 + fm * 16 + l15, cb);
#pragma unroll
        for (int fn = 0; fn < 2; fn++) {
            bf16x8 bg = ldfrag32(sBgc, wn * 32 + fn * 16 + l15, cb);
            bf16x8 bu = ldfrag32(sBuc, wn * 32 + fn * 16 + l15, cb);
#pragma unroll
            for (int fm = 0; fm < 4; fm++) {
                accg[fm][fn] = __builtin_amdgcn_mfma_f32_16x16x32_bf16(a[fm], bg, accg[fm][fn], 0, 0, 0);
                accu[fm][fn] = __builtin_amdgcn_mfma_f32_16x16x32_bf16(a[fm], bu, accu[fm][fn], 0, 0, 0);
            }
        }

        if (pf) {
            stage8v((char*)sBg[nxt], br, bc * 16, g0, g1);
            stage8v((char*)sBu[nxt], br, bc * 16, u0, u1);
        }
        __syncthreads();   // drains A(k+1) glds + B(k+1) (both issued before MFMA)
    }

    // epilogue: silu(gate)*up -> act (bf16)
#pragma unroll
    for (int fm = 0; fm < 4; fm++) {
#pragma unroll
        for (int fn = 0; fn < 2; fn++) {
#pragma unroll
            for (int j = 0; j < 4; j++) {
                int mloc = wm * 64 + fm * 16 + lh * 4 + j;
                int gg = m0 + mloc;
                if (gg < cnt) {
                    float gv = accg[fm][fn][j];
                    float uv = accu[fm][fn][j];
                    float sv = gv * (1.0f / (1.0f + __expf(-gv)));
                    int n = n0 + wn * 32 + fn * 16 + l15;
                    act[((size_t)e * T_TOK + gg) * ID + n] = (__bf16)(sv * uv);
                }
            }
        }
    }
}

// --- GEMM2: out[tok] += (act @ Dn^T) * wt  (fp32 atomic scatter) --------
// grid.x = ((e*32 + n) << 4) + m; same schedule; 24KB LDS.

__global__ __launch_bounds__(256, 4) void k_gemm2(
    const __bf16* __restrict__ act, const float* __restrict__ dn,
    const int* __restrict__ counts, const int* __restrict__ tok,
    const float* __restrict__ wts, float* __restrict__ out) {
    int x = blockIdx.x;
    int m = x & 15;
    int g = x >> 4;
    int e = g >> 5;
    int n0 = (g & 31) * BN;
    int cnt = counts[e];
    int m0 = m * BM;
    if (m0 >= cnt) return;

    __shared__ __align__(16) __bf16 sA[2][BM * BK];
    __shared__ __align__(16) __bf16 sB[2][BN * BK];
    __shared__ int tokLds[BM];
    __shared__ float wtLds[BM];

    int tid = threadIdx.x;
    if (tid < BM) {
        int gg = m0 + tid;
        bool v = gg < cnt;
        tokLds[tid] = v ? tok[e * T_TOK + gg] : 0;
        wtLds[tid] = v ? wts[e * T_TOK + gg] : 0.f;
    }

    int lane = tid & 63;
    int wid = tid >> 6;

    const __bf16* pA[2];
    int csw = ((lane & 3) ^ ((lane >> 2) & 3)) * 8;
#pragma unroll
    for (int j = 0; j < 2; j++) {
        int r = 32 * wid + 16 * j + (lane >> 2);
        pA[j] = act + ((size_t)e * T_TOK + m0 + r) * ID + csw;
    }

    int br = tid >> 2, bc = tid & 3;
    const float* bSrc = dn + (size_t)e * HD * ID + (size_t)(n0 + br) * ID + bc * 8;

    int wm = wid >> 1, wn = wid & 1;
    int l15 = lane & 15, lh = lane >> 4;

    f32x4 acc[4][2] = {};

    const int NT = ID / BK;   // 44

    {
        float4 b0 = ((const float4*)bSrc)[0], b1 = ((const float4*)bSrc)[1];
#pragma unroll
        for (int j = 0; j < 2; j++)
            GLDS16(pA[j], &sA[0][(32 * wid + 16 * j) * BK]);
        stage8v((char*)sB[0], br, bc * 16, b0, b1);
    }
    __syncthreads();

    for (int k = 0; k < NT; k++) {
        int cur = k & 1, nxt = cur ^ 1;
        bool pf = (k + 1 < NT);
        float4 b0, b1;
        if (pf) {
            int k0 = (k + 1) * BK;
#pragma unroll
            for (int j = 0; j < 2; j++)
                GLDS16(pA[j] + k0, &sA[nxt][(32 * wid + 16 * j) * BK]);
            const float* bs = bSrc + k0;
            b0 = ((const float4*)bs)[0]; b1 = ((const float4*)bs)[1];
        }

        const __bf16* sAc = sA[cur];
        const __bf16* sBc = sB[cur];
        int cb = lh * 16;
        bf16x8 a[4];
#pragma unroll
        for (int fm = 0; fm < 4; fm++)
            a[fm] = ldfrag32(sAc, wm * 64 + fm * 16 + l15, cb);
#pragma unroll
        for (int fn = 0; fn < 2; fn++) {
            bf16x8 b = ldfrag32(sBc, wn * 32 + fn * 16 + l15, cb);
#pragma unroll
            for (int fm = 0; fm < 4; fm++)
                acc[fm][fn] = __builtin_amdgcn_mfma_f32_16x16x32_bf16(a[fm], b, acc[fm][fn], 0, 0, 0);
        }

        if (pf) stage8v((char*)sB[nxt], br, bc * 16, b0, b1);
        __syncthreads();
    }

#pragma unroll
    for (int fm = 0; fm < 4; fm++) {
#pragma unroll
        for (int fn = 0; fn < 2; fn++) {
#pragma unroll
            for (int j = 0; j < 4; j++) {
                int mloc = wm * 64 + fm * 16 + lh * 4 + j;
                int gg = m0 + mloc;
                if (gg < cnt) {
                    float v = acc[fm][fn][j] * wtLds[mloc];
                    int n = n0 + wn * 32 + fn * 16 + l15;
                    atomicAdd(&out[(size_t)tokLds[mloc] * HD + n], v);
                }
            }
        }
    }
}

// --- launch --------------------------------------------------------------

extern "C" void kernel_launch(void* const* d_in, const int* in_sizes, int n_in,
                              void* d_out, int out_size, void* d_ws, size_t ws_size,
                              hipStream_t stream) {
    const float* hs = (const float*)d_in[0];
    const int* tki = (const int*)d_in[1];
    const float* tkw = (const float*)d_in[2];
    const float* gup = (const float*)d_in[3];
    const float* dnp = (const float*)d_in[4];
    float* out = (float*)d_out;

    char* p = (char*)d_ws;
    int* counts = (int*)p;      p += 256;
    float* combine = (float*)p; p += (size_t)T_TOK * NE * 4;
    int* tok = (int*)p;         p += (size_t)NE * T_TOK * 4;
    float* wts = (float*)p;     p += (size_t)NE * T_TOK * 4;
    __bf16* Xb = (__bf16*)p;    p += (size_t)T_TOK * HD * 2;
    __bf16* act = (__bf16*)p;   // NE*T_TOK*ID*2 = 92MB

    hipMemsetAsync(counts, 0, 256, stream);
    hipMemsetAsync(d_out, 0, (size_t)T_TOK * HD * 4, stream);
    k_combine<<<T_TOK / 256, 256, 0, stream>>>(tki, tkw, combine);
    k_lists<<<T_TOK / 256, 256, 0, stream>>>(combine, counts, tok, wts);
    k_cvt<<<(T_TOK * HD / 8) / 256, 256, 0, stream>>>(hs, Xb);
    k_gemm1<<<dim3(22 * NE * 16), 256, 0, stream>>>(Xb, gup, counts, tok, act);
    k_gemm2<<<dim3(32 * NE * 16), 256, 0, stream>>>(act, dnp, counts, tok, wts, out);
}

// Round 8
// 443.114 us; speedup vs baseline: 2.5586x; 2.5586x over previous
//
#include <hip/hip_runtime.h>
#include <hip/hip_bf16.h>
#include <cstdint>

#define T_TOK 2048
#define HD 2048
#define ID 1408
#define NE 16
#define TOPK 6

#define BM 256
#define BN 64
#define BK 64
#define NT1 22   // ID/BN   (gemm1 n-tiles)
#define NT2 32   // HD/BN   (gemm2 n-tiles)

typedef __bf16 bf16x8 __attribute__((ext_vector_type(8)));
typedef float f32x4 __attribute__((ext_vector_type(4)));

typedef const __attribute__((address_space(1))) void* gas1_t;
typedef __attribute__((address_space(3))) void* las3_t;
#define GLDS16(g, l) __builtin_amdgcn_global_load_lds((gas1_t)(g), (las3_t)(l), 16, 0, 0)

// --- small kernels -----------------------------------------------------

__global__ void k_combine(const int* __restrict__ idx, const float* __restrict__ w,
                          float* __restrict__ combine) {
    int t = blockIdx.x * blockDim.x + threadIdx.x;
    if (t >= T_TOK) return;
    int ie[TOPK];
    float fw[TOPK];
#pragma unroll
    for (int k = 0; k < TOPK; k++) { ie[k] = idx[t * TOPK + k]; fw[k] = w[t * TOPK + k]; }
#pragma unroll
    for (int e = 0; e < NE; e++) {
        float s = 0.f;
#pragma unroll
        for (int k = 0; k < TOPK; k++) if (ie[k] == e) s += fw[k];
        combine[t * NE + e] = s;
    }
}

__global__ void k_lists(const float* __restrict__ combine, int* __restrict__ counts,
                        int* __restrict__ tok, float* __restrict__ wts) {
    int t = blockIdx.x * blockDim.x + threadIdx.x;
    if (t >= T_TOK) return;
    for (int e = 0; e < NE; e++) {
        float c = combine[t * NE + e];
        if (c != 0.0f) {
            int p = atomicAdd(&counts[e], 1);
            tok[e * T_TOK + p] = t;
            wts[e * T_TOK + p] = c;
        }
    }
}

__global__ void k_cvt(const float* __restrict__ x, __bf16* __restrict__ xb) {
    int i = (blockIdx.x * 256 + threadIdx.x) * 8;
    float4 a = *(const float4*)(x + i);
    float4 b = *(const float4*)(x + i + 4);
    bf16x8 o;
    o[0] = (__bf16)a.x; o[1] = (__bf16)a.y; o[2] = (__bf16)a.z; o[3] = (__bf16)a.w;
    o[4] = (__bf16)b.x; o[5] = (__bf16)b.y; o[6] = (__bf16)b.z; o[7] = (__bf16)b.w;
    *(bf16x8*)(xb + i) = o;
}

// --- LDS helpers (128-byte rows, BK=64) ---------------------------------

__device__ __forceinline__ int swz(int row, int cb) {
    // rows are 128B; XOR-swizzle bits 4..6 by row&7 (Guideline 4)
    return row * 128 + (cb ^ ((row & 7) << 4));
}

__device__ __forceinline__ bf16x8 ldfrag(const __bf16* base, int row, int cb) {
    return *(const bf16x8*)((const char*)base + swz(row, cb));
}

// stage 8 fp32 -> 8 bf16 into LDS (one swizzled 16B store)
__device__ __forceinline__ void stage8(const float* __restrict__ src, char* lds,
                                       int row, int cb) {
    float4 f0 = ((const float4*)src)[0];
    float4 f1 = ((const float4*)src)[1];
    bf16x8 o;
    o[0] = (__bf16)f0.x; o[1] = (__bf16)f0.y; o[2] = (__bf16)f0.z; o[3] = (__bf16)f0.w;
    o[4] = (__bf16)f1.x; o[5] = (__bf16)f1.y; o[6] = (__bf16)f1.z; o[7] = (__bf16)f1.w;
    *(bf16x8*)(lds + swz(row, cb)) = o;
}

// Decode a live work item: items are e-major, m fastest within e.
// nm_e = ceil(counts[e]/BM). Returns false if item id past total.
__device__ __forceinline__ bool decode_item(const int* cnts, int it, int ntn,
                                            int& e, int& m, int& n, int& cnt) {
    int r = it;
#pragma unroll
    for (int ee = 0; ee < NE; ee++) {
        int c = cnts[ee];
        int nm = (c + BM - 1) >> 8;    // BM = 256
        int tot = nm * ntn;
        if (r < tot) { e = ee; m = r % nm; n = r / nm; cnt = c; return true; }
        r -= tot;
    }
    return false;
}

// --- GEMM1: act = silu(X@Gg^T) * (X@Gu^T)  ------------------------------
// Persistent blocks + atomic cursor over live (e,m,n) items.
// Inner K-loop identical to R3 (295us): sync; glds A(k) + stage B(k); sync; MFMA.

__global__ __launch_bounds__(512, 4) void k_gemm1(
    const __bf16* __restrict__ Xb, const float* __restrict__ gup,
    const int* __restrict__ counts, const int* __restrict__ tok,
    __bf16* __restrict__ act, int* __restrict__ cursor) {
    __shared__ __align__(16) __bf16 sA[BM * BK];
    __shared__ __align__(16) __bf16 sBg[BN * BK];
    __shared__ __align__(16) __bf16 sBu[BN * BK];
    __shared__ int s_it;

    int tid = threadIdx.x;
    int lane = tid & 63;
    int wid = tid >> 6;
    int wm = wid >> 1, wn = wid & 1;           // 4x2 waves over 256x64
    int l15 = lane & 15, lh = lane >> 4;
    int csw = ((lane & 7) ^ ((lane >> 3) & 7)) * 8;
    int br = tid >> 3, bc = tid & 7;

    int cnts[NE];
#pragma unroll
    for (int ee = 0; ee < NE; ee++) cnts[ee] = counts[ee];

    while (true) {
        if (tid == 0) s_it = atomicAdd(cursor, 1);
        __syncthreads();                        // also fences LDS reuse across items
        int e, m, n, cnt;
        if (!decode_item(cnts, s_it, NT1, e, m, n, cnt)) break;
        int m0 = m * BM;
        int n0 = n * BN;

        const __bf16* pA[4];
#pragma unroll
        for (int j = 0; j < 4; j++) {
            int r = 32 * wid + 8 * j + (lane >> 3);
            int g = m0 + r;
            if (g >= cnt) g = cnt - 1;
            pA[j] = Xb + (size_t)tok[e * T_TOK + g] * HD + csw;
        }
        const float* gbase = gup + (size_t)e * (2 * ID) * HD;
        const float* bgSrc = gbase + (size_t)(n0 + br) * HD + bc * 8;
        const float* buSrc = gbase + (size_t)(ID + n0 + br) * HD + bc * 8;

        f32x4 accg[4][2] = {};
        f32x4 accu[4][2] = {};

        for (int k0 = 0; k0 < HD; k0 += BK) {
            __syncthreads();
#pragma unroll
            for (int j = 0; j < 4; j++)
                GLDS16(pA[j] + k0, &sA[(32 * wid + 8 * j) * BK]);
            stage8(bgSrc + k0, (char*)sBg, br, bc * 16);
            stage8(buSrc + k0, (char*)sBu, br, bc * 16);
            __syncthreads();
#pragma unroll
            for (int kk = 0; kk < 2; kk++) {
                int cb = kk * 64 + lh * 16;
                bf16x8 a[4];
#pragma unroll
                for (int fm = 0; fm < 4; fm++)
                    a[fm] = ldfrag(sA, wm * 64 + fm * 16 + l15, cb);
#pragma unroll
                for (int fn = 0; fn < 2; fn++) {
                    bf16x8 bg = ldfrag(sBg, wn * 32 + fn * 16 + l15, cb);
                    bf16x8 bu = ldfrag(sBu, wn * 32 + fn * 16 + l15, cb);
#pragma unroll
                    for (int fm = 0; fm < 4; fm++) {
                        accg[fm][fn] = __builtin_amdgcn_mfma_f32_16x16x32_bf16(a[fm], bg, accg[fm][fn], 0, 0, 0);
                        accu[fm][fn] = __builtin_amdgcn_mfma_f32_16x16x32_bf16(a[fm], bu, accu[fm][fn], 0, 0, 0);
                    }
                }
            }
        }

        // epilogue: silu(gate)*up -> act (bf16)
#pragma unroll
        for (int fm = 0; fm < 4; fm++) {
#pragma unroll
            for (int fn = 0; fn < 2; fn++) {
#pragma unroll
                for (int j = 0; j < 4; j++) {
                    int mloc = wm * 64 + fm * 16 + lh * 4 + j;
                    int g = m0 + mloc;
                    if (g < cnt) {
                        float gv = accg[fm][fn][j];
                        float uv = accu[fm][fn][j];
                        float sv = gv * (1.0f / (1.0f + __expf(-gv)));
                        int nn = n0 + wn * 32 + fn * 16 + l15;
                        act[((size_t)e * T_TOK + g) * ID + nn] = (__bf16)(sv * uv);
                    }
                }
            }
        }
    }
}

// --- GEMM2: out[tok] += (act @ Dn^T) * wt  (fp32 atomic scatter) --------

__global__ __launch_bounds__(512, 4) void k_gemm2(
    const __bf16* __restrict__ act, const float* __restrict__ dn,
    const int* __restrict__ counts, const int* __restrict__ tok,
    const float* __restrict__ wts, float* __restrict__ out,
    int* __restrict__ cursor) {
    __shared__ __align__(16) __bf16 sA[BM * BK];
    __shared__ __align__(16) __bf16 sB[BN * BK];
    __shared__ int tokLds[BM];
    __shared__ float wtLds[BM];
    __shared__ int s_it;

    int tid = threadIdx.x;
    int lane = tid & 63;
    int wid = tid >> 6;
    int wm = wid >> 1, wn = wid & 1;
    int l15 = lane & 15, lh = lane >> 4;
    int csw = ((lane & 7) ^ ((lane >> 3) & 7)) * 8;
    int br = tid >> 3, bc = tid & 7;

    int cnts[NE];
#pragma unroll
    for (int ee = 0; ee < NE; ee++) cnts[ee] = counts[ee];

    while (true) {
        if (tid == 0) s_it = atomicAdd(cursor, 1);
        __syncthreads();                        // fences LDS (incl. tokLds) across items
        int e, m, n, cnt;
        if (!decode_item(cnts, s_it, NT2, e, m, n, cnt)) break;
        int m0 = m * BM;
        int n0 = n * BN;

        if (tid < BM) {
            int g = m0 + tid;
            bool v = g < cnt;
            tokLds[tid] = v ? tok[e * T_TOK + g] : 0;
            wtLds[tid] = v ? wts[e * T_TOK + g] : 0.f;
        }

        const __bf16* pA[4];
#pragma unroll
        for (int j = 0; j < 4; j++) {
            int r = 32 * wid + 8 * j + (lane >> 3);
            int g = m0 + r;
            if (g >= cnt) g = cnt - 1;
            pA[j] = act + ((size_t)e * T_TOK + g) * ID + csw;
        }
        const float* bSrc = dn + (size_t)e * HD * ID + (size_t)(n0 + br) * ID + bc * 8;

        f32x4 acc[4][2] = {};

        for (int k0 = 0; k0 < ID; k0 += BK) {
            __syncthreads();
#pragma unroll
            for (int j = 0; j < 4; j++)
                GLDS16(pA[j] + k0, &sA[(32 * wid + 8 * j) * BK]);
            stage8(bSrc + k0, (char*)sB, br, bc * 16);
            __syncthreads();
#pragma unroll
            for (int kk = 0; kk < 2; kk++) {
                int cb = kk * 64 + lh * 16;
                bf16x8 a[4];
#pragma unroll
                for (int fm = 0; fm < 4; fm++)
                    a[fm] = ldfrag(sA, wm * 64 + fm * 16 + l15, cb);
#pragma unroll
                for (int fn = 0; fn < 2; fn++) {
                    bf16x8 b = ldfrag(sB, wn * 32 + fn * 16 + l15, cb);
#pragma unroll
                    for (int fm = 0; fm < 4; fm++)
                        acc[fm][fn] = __builtin_amdgcn_mfma_f32_16x16x32_bf16(a[fm], b, acc[fm][fn], 0, 0, 0);
                }
            }
        }

        __syncthreads();   // epilogue reads tokLds; keep it ordered vs next item
#pragma unroll
        for (int fm = 0; fm < 4; fm++) {
#pragma unroll
            for (int fn = 0; fn < 2; fn++) {
#pragma unroll
                for (int j = 0; j < 4; j++) {
                    int mloc = wm * 64 + fm * 16 + lh * 4 + j;
                    int g = m0 + mloc;
                    if (g < cnt) {
                        float v = acc[fm][fn][j] * wtLds[mloc];
                        int nn = n0 + wn * 32 + fn * 16 + l15;
                        atomicAdd(&out[(size_t)tokLds[mloc] * HD + nn], v);
                    }
                }
            }
        }
    }
}

// --- launch --------------------------------------------------------------

extern "C" void kernel_launch(void* const* d_in, const int* in_sizes, int n_in,
                              void* d_out, int out_size, void* d_ws, size_t ws_size,
                              hipStream_t stream) {
    const float* hs = (const float*)d_in[0];
    const int* tki = (const int*)d_in[1];
    const float* tkw = (const float*)d_in[2];
    const float* gup = (const float*)d_in[3];
    const float* dnp = (const float*)d_in[4];
    float* out = (float*)d_out;

    char* p = (char*)d_ws;
    int* counts = (int*)p;      p += 256;
    int* cursors = (int*)p;     p += 256;       // [0]=gemm1, [1]=gemm2
    float* combine = (float*)p; p += (size_t)T_TOK * NE * 4;
    int* tok = (int*)p;         p += (size_t)NE * T_TOK * 4;
    float* wts = (float*)p;     p += (size_t)NE * T_TOK * 4;
    __bf16* Xb = (__bf16*)p;    p += (size_t)T_TOK * HD * 2;
    __bf16* act = (__bf16*)p;   // NE*T_TOK*ID*2 = 92MB

    hipMemsetAsync(counts, 0, 512, stream);     // counts + cursors
    hipMemsetAsync(d_out, 0, (size_t)T_TOK * HD * 4, stream);
    k_combine<<<T_TOK / 256, 256, 0, stream>>>(tki, tkw, combine);
    k_lists<<<T_TOK / 256, 256, 0, stream>>>(combine, counts, tok, wts);
    k_cvt<<<(T_TOK * HD / 8) / 256, 256, 0, stream>>>(hs, Xb);
    k_gemm1<<<dim3(768), 512, 0, stream>>>(Xb, gup, counts, tok, act, &cursors[0]);
    k_gemm2<<<dim3(768), 512, 0, stream>>>(act, dnp, counts, tok, wts, out, &cursors[1]);
}